// Round 9
// baseline (120.607 us; speedup 1.0000x reference)
//
#include <hip/hip_runtime.h>
#include <hip/hip_bf16.h>
#include <math.h>

#define N_TOT 8192
#define HALF_N 4096
#define D_DIM 512
#define BM 128         // tile edge (128x128 tiles)
#define BK 64          // fp8 bytes per K-step; 8 K-steps
#define NKIT (D_DIM / BK)
#define NTILES 2080    // 64*65/2 upper-triangle 128x128 tiles
#define THREADS 512    // 8 thin waves

// s_waitcnt imm: vmcnt[3:0] | expcnt<<4 | lgkmcnt<<8 (expcnt/lgkmcnt = max -> unconstrained)
#define WAIT_VM0 0xF70

typedef float f32x4_t __attribute__((ext_vector_type(4)));
typedef long long i64x2 __attribute__((ext_vector_type(2)));

typedef __attribute__((address_space(1))) unsigned int g_u32;
typedef __attribute__((address_space(3))) unsigned int l_u32;

// Kernel 1: L2-normalize rows of [p1;p2] -> fp8 e4m3 Z in k-PERMUTED layout
// (validated R9/R11): within each 64B k-block, source byte k (q=(k>>3)&3,
// h=(k>>5)&1) stored at q*16 + h*8 + (k&7). Both GEMM operands use the same
// bijection, so dot products are unaffected; a lane's two 8B MFMA k-pieces
// are one contiguous 16B chunk -> single ds_read_b128 / global dwordx4.
__global__ __launch_bounds__(256) void k_normalize(
    const float* __restrict__ p1, const float* __restrict__ p2,
    unsigned char* __restrict__ zf8, float* __restrict__ rowsum,
    float* __restrict__ out)
{
    const int w = threadIdx.x >> 6;
    const int lane = threadIdx.x & 63;
    const int row = blockIdx.x * 4 + w;

    if (threadIdx.x < 4) rowsum[blockIdx.x * 4 + threadIdx.x] = 0.0f;
    if (blockIdx.x == 0 && threadIdx.x == 0) out[0] = 0.0f;

    const float* src = (row < HALF_N) ? p1 + (size_t)row * D_DIM
                                      : p2 + (size_t)(row - HALF_N) * D_DIM;
    float4 a = *(const float4*)(src + lane * 4);
    float4 b = *(const float4*)(src + 256 + lane * 4);
    float s = a.x*a.x + a.y*a.y + a.z*a.z + a.w*a.w
            + b.x*b.x + b.y*b.y + b.z*b.z + b.w*b.w;
    #pragma unroll
    for (int m = 1; m < 64; m <<= 1) s += __shfl_xor(s, m, 64);
    float inv = 1.0f / fmaxf(sqrtf(s), 1e-8f);

    int pk0 = __builtin_amdgcn_cvt_pk_fp8_f32(a.x * inv, a.y * inv, 0, false);
    pk0     = __builtin_amdgcn_cvt_pk_fp8_f32(a.z * inv, a.w * inv, pk0, true);
    int pk1 = __builtin_amdgcn_cvt_pk_fp8_f32(b.x * inv, b.y * inv, 0, false);
    pk1     = __builtin_amdgcn_cvt_pk_fp8_f32(b.z * inv, b.w * inv, pk1, true);

    unsigned char* dst = zf8 + (size_t)row * D_DIM;
    const int o0 = lane * 4;
    const int o1 = 256 + lane * 4;
    const int d0 = (o0 & ~63) + ((o0 >> 3) & 3) * 16 + ((o0 >> 5) & 1) * 8 + (o0 & 4);
    const int d1 = (o1 & ~63) + ((o1 >> 3) & 3) * 16 + ((o1 >> 5) & 1) * 8 + (o1 & 4);
    *(int*)(dst + d0) = pk0;
    *(int*)(dst + d1) = pk1;
}

// Kernel 2: upper-triangle 128x128 tiles of sim = Z*Z^T, fp8 MFMA 16x16x32.
// ROUND 8 lesson (cycle accounting from counters): at 48.1us the per-block
// K-step is a SERIAL chain {48 ds_read_b128 (576cy) + stage (260cy) + MFMA
// (620cy)} x 8 K x 8.1 blk/CU ~= 48us exactly -- LDS traffic is co-critical
// with MFMA and the lockstep phases don't overlap (MfmaUtil 27 / VALU 28).
// LDS bytes/lane/K-step = Mw+Nw regardless of shape/waves; the only cut is
// removing an operand from LDS. ROUND 9: B DIRECT GLOBAL->REG. k-permuted
// layout makes a lane's B-fragment one contiguous 16B at
// row*512 + it*64 + q*16 (no swizzle needed from global; the chunk-XOR was
// only LDS slot placement). LDS reads 6->4 b128/lane, stage-writes halve
// (A only, 16 KB dbuf), and B rides the VMEM pipe -- truly parallel to the
// LDS pipe. B(it+1) loads issue after the barrier (a full K-step of cover,
// same proven pattern as A-stage); top-of-loop vm0 drains both. L2 B-traffic
// 272 MB aggregate ~ 8us at L2 BW. Everything else R8-proven: thin-wave
// 64x32 per-wave tile, chunk^((r>>1)&3) A-slot swizzle (0 conflicts),
// XCD swizzle (2080=8*260), stage-after-barrier, epilogue.
__global__ __launch_bounds__(THREADS, 4) void k_gemm(
    const unsigned char* __restrict__ zf8,
    float* __restrict__ rowsum, float* __restrict__ pos)
{
    __shared__ __align__(16) unsigned char As[2][BM * BK];  // 2 x 8 KB (A only)

    const int tid = threadIdx.x;
    const int lane = tid & 63;
    const int w = tid >> 6;              // 0..7
    const int wr = w >> 2, wc = w & 3;   // wave grid 2 x 4: 64-row x 32-col per wave
    const int q = lane >> 4, l15 = lane & 15;

    // XCD-aware bijective swizzle (2080 = 8 * 260): consecutive t share bx
    // runs -> same-XCD L2 reuse of the B panel (now read every K-step).
    const int t0 = blockIdx.x;
    const int t = (t0 & 7) * (NTILES / 8) + (t0 >> 3);

    // triangular block mapping: t -> (bx >= by)
    int bi = (int)((sqrtf(8.0f * (float)t + 1.0f) - 1.0f) * 0.5f);
    while ((bi + 1) * (bi + 2) / 2 <= t) ++bi;
    while (bi * (bi + 1) / 2 > t) --bi;
    const int bx = bi;                       // col tile (larger)
    const int by = t - bi * (bi + 1) / 2;    // row tile
    const bool isDiag = (bx == by);
    const bool hasPos = (bx - by == (HALF_N / BM));   // == 32
    const int rowBase = by * BM;
    const int colBase = bx * BM;

    // A staging: 16B chunks; 128 rows x 4 chunks = 512 chunks = 1/thread.
    // LDS slot cc of row r holds source chunk cc ^ ((r>>1)&3) (R8/R11 swizzle).
    const int r0 = tid >> 2, cc0 = tid & 3;
    const int gc0 = cc0 ^ ((r0 >> 1) & 3);
    const unsigned char* gA = zf8 + (size_t)(rowBase + r0) * D_DIM + gc0 * 16;

    auto stageA = [&](int buf, int kblk) {
        __builtin_amdgcn_global_load_lds((const g_u32*)(gA + kblk * BK),
                                         (l_u32*)&As[buf][tid * 16], 16, 0, 0);
    };

    // B direct-from-global per-lane fragment base: row = colBase+wc*32+j*16+l15,
    // byte = row*512 + it*64 + q*16. j=1 adds 16 rows = 8192 bytes.
    const unsigned char* gBd = zf8 + (size_t)(colBase + wc * 32 + l15) * D_DIM + q * 16;

    // precomputed per-lane A fragment byte offsets within one 8 KB buffer
    int aOff[4];
    #pragma unroll
    for (int i = 0; i < 4; i++) {
        const int ra = wr * 64 + i * 16 + l15;
        aOff[i] = ra * BK + (q ^ ((ra >> 1) & 3)) * 16;
    }

    f32x4_t acc[4][2] = {};

    // prologue: stage A(0), load B(0)
    stageA(0, 0);
    i64x2 bC0 = *(const i64x2*)(gBd);
    i64x2 bC1 = *(const i64x2*)(gBd + 8192);

    #pragma unroll
    for (int it = 0; it < NKIT; it++) {
        const int cur = it & 1;
        // drains: A-stage(it) + B-loads feeding this iter (issued >= 1 K-step
        // ago -> covered wait); barrier publishes A(it) across waves.
        __builtin_amdgcn_s_waitcnt(WAIT_VM0);
        __builtin_amdgcn_s_barrier();

        i64x2 bN0, bN1;
        if (it + 1 < NKIT) {
            stageA(cur ^ 1, it + 1);
            bN0 = *(const i64x2*)(gBd + (it + 1) * BK);
            bN1 = *(const i64x2*)(gBd + 8192 + (it + 1) * BK);
        }

        i64x2 aF[4];
        #pragma unroll
        for (int i = 0; i < 4; i++) aF[i] = *(const i64x2*)&As[cur][aOff[i]];

        __builtin_amdgcn_s_setprio(1);
        #pragma unroll
        for (int h = 0; h < 2; h++)
            #pragma unroll
            for (int i = 0; i < 4; i++) {
                acc[i][0] = __builtin_amdgcn_mfma_f32_16x16x32_fp8_fp8(
                    aF[i][h], bC0[h], acc[i][0], 0, 0, 0);
                acc[i][1] = __builtin_amdgcn_mfma_f32_16x16x32_fp8_fp8(
                    aF[i][h], bC1[h], acc[i][1], 0, 0, 0);
            }
        __builtin_amdgcn_s_setprio(0);

        if (it + 1 < NKIT) { bC0 = bN0; bC1 = bN1; }
        // reads of As[cur] are in regs (lgkm-waited before MFMA), so next
        // iteration's stage into cur is WAW-safe after its top barrier.
    }

    // Epilogue. C/D layout (16x16 family): col = lane&15, row = (lane>>4)*4 + reg.
    float colacc[2] = {0.f, 0.f};
    #pragma unroll
    for (int i = 0; i < 4; i++) {
        #pragma unroll
        for (int r = 0; r < 4; r++) {
            const int row = rowBase + wr * 64 + i * 16 + q * 4 + r;
            float rs = 0.0f;
            #pragma unroll
            for (int j = 0; j < 2; j++) {
                const int col = colBase + wc * 32 + j * 16 + l15;
                const float c = acc[i][j][r];
                float e = __expf(c);
                if (isDiag && col == row) e = 0.0f;
                rs += e;
                colacc[j] += e;
                if (hasPos && col == row + HALF_N) { pos[row] = c; pos[col] = c; }
            }
            rs += __shfl_xor(rs, 1); rs += __shfl_xor(rs, 2);
            rs += __shfl_xor(rs, 4); rs += __shfl_xor(rs, 8);
            if (l15 == 0) atomicAdd(&rowsum[row], rs);
        }
    }
    if (!isDiag) {
        #pragma unroll
        for (int j = 0; j < 2; j++) {
            float cs = colacc[j];
            cs += __shfl_xor(cs, 16);
            cs += __shfl_xor(cs, 32);
            if (q == 0) atomicAdd(&rowsum[colBase + wc * 32 + j * 16 + l15], cs);
        }
    }
}

// Kernel 3: mean over rows of (log(rowsum) - pos) -> scalar (out pre-zeroed).
__global__ __launch_bounds__(256) void k_finalize(
    const float* __restrict__ rowsum, const float* __restrict__ pos,
    float* __restrict__ out)
{
    const int t = threadIdx.x;
    const int i = blockIdx.x * 256 + t;
    float s = logf(rowsum[i]) - pos[i];
    #pragma unroll
    for (int m = 1; m < 64; m <<= 1) s += __shfl_xor(s, m, 64);
    __shared__ float red[4];
    if ((t & 63) == 0) red[t >> 6] = s;
    __syncthreads();
    if (t == 0)
        atomicAdd(out, (red[0] + red[1] + red[2] + red[3]) * (1.0f / (float)N_TOT));
}

extern "C" void kernel_launch(void* const* d_in, const int* in_sizes, int n_in,
                              void* d_out, int out_size, void* d_ws, size_t ws_size,
                              hipStream_t stream) {
    const float* p1 = (const float*)d_in[0];
    const float* p2 = (const float*)d_in[1];

    unsigned char* zf8 = (unsigned char*)d_ws;                          // 4 MB
    float* rowsum = (float*)((char*)d_ws + (size_t)N_TOT * D_DIM);      // 32 KB
    float* pos    = rowsum + N_TOT;                                     // 32 KB
    float* outp   = (float*)d_out;

    k_normalize<<<N_TOT / 4, 256, 0, stream>>>(p1, p2, zf8, rowsum, outp);
    k_gemm<<<NTILES, THREADS, 0, stream>>>(zf8, rowsum, pos);
    k_finalize<<<N_TOT / 256, 256, 0, stream>>>(rowsum, pos, outp);
}